// Round 15
// baseline (109.248 us; speedup 1.0000x reference)
//
#include <hip/hip_runtime.h>
#include <hip/hip_bf16.h>

// Problem dims (fixed by reference setup_inputs)
#define NQ 8
#define NK 1024
#define ND 64
#define NH 1024
#define NB 8
#define NT 8192

typedef float  vfloat4 __attribute__((ext_vector_type(4)));
typedef float  vfloat2 __attribute__((ext_vector_type(2)));
typedef float  f32x4   __attribute__((ext_vector_type(4)));
typedef short  short8  __attribute__((ext_vector_type(8)));

// HW packed f32->bf16 (RNE) — used only in to_bf16 (R10/R11-verified there).
__device__ __forceinline__ unsigned cvt_pk_bf16(float lo, float hi) {
    unsigned r;
    asm("v_cvt_pk_bf16_f32 %0, %1, %2" : "=v"(r) : "v"(lo), "v"(hi));
    return r;
}
// Scalar RNE pack (R4-R8-verified) — used in the fused kernel (no asm there).
__device__ __forceinline__ unsigned bf16_rne(float f) {
    unsigned u = __float_as_uint(f);
    return (u + 0x7fffu + ((u >> 16) & 1u)) >> 16;
}

// ------------- Kernel 0: convert cb and W to bf16 (exact R11) --------------
__global__ __launch_bounds__(256) void to_bf16(const float* __restrict__ cb,
                                               const float* __restrict__ W,
                                               uint4* __restrict__ cbh,
                                               uint4* __restrict__ Wh) {
    int half = blockIdx.x >> 8;
    int i    = ((blockIdx.x & 255) << 8) + threadIdx.x;  // 0..65535
    const float4* src = (const float4*)(half ? W : cb);
    float4 a = src[i * 2], b = src[i * 2 + 1];
    uint4 o;
    o.x = cvt_pk_bf16(a.x, a.y);
    o.y = cvt_pk_bf16(a.z, a.w);
    o.z = cvt_pk_bf16(b.x, b.y);
    o.w = cvt_pk_bf16(b.z, b.w);
    (half ? Wh : cbh)[i] = o;
}

// ------------- Fused kernel: build 4h P-slice in LDS (MFMA), gather --------
// out[b,h,t] = sum_q P[q, codes[q,b,t], h] + bsum[h]
// Changes vs the two NaN attempts (R13/R14): A rows are DISTINCT
// (h0+row16, clamped; exact R11 load geometry — clamp only feeds discarded
// C rows 4..15), pack via bf16_rne computed non-divergently (no asm in this
// kernel), ws offsets back at +16MB, and Pl is ZERO-INITIALIZED so a
// coverage hole reads 0 (finite absmax ~30 diagnostic) instead of garbage.
// Phase-2 is the verbatim R12 gather body + f32 bias epilogue.
__global__ __launch_bounds__(512) void fused_rvq(const int* __restrict__ codes,
                                                 const short* __restrict__ cbh,
                                                 const short* __restrict__ Wh,
                                                 const float* __restrict__ bias,
                                                 float* __restrict__ out) {
    __shared__ uint2 Pl[NQ * NK];  // 64 KB: [q][k] -> 4 bf16 (h0..h0+3)

    int hb = blockIdx.x >> 1;      // 0..255 h-blocks of 4
    int th = blockIdx.x & 1;       // t-half
    int h0 = hb * 4;
    int tid  = threadIdx.x;
    int wave = tid >> 6, lane = tid & 63;
    int row16 = lane & 15, grp = lane >> 4;

    // zero-init Pl (diagnostic: hole -> finite error, not NaN)
    uint2 z; z.x = 0u; z.y = 0u;
#pragma unroll
    for (int i = 0; i < 16; ++i) Pl[tid + i * 512] = z;
    __syncthreads();

    // ---- Phase 1: build Pl via MFMA; wave w owns q=w, 64 k-tiles ----
    {
        int q = wave;
        int hrow = h0 + row16;                 // distinct rows, R11 geometry
        if (hrow > NH - 1) hrow = NH - 1;      // clamp feeds only C rows 4..15
        const short* wrow = Wh + ((size_t)q * NH + hrow) * ND + grp * 8;
        short8 a0 = *(const short8*)(wrow);
        short8 a1 = *(const short8*)(wrow + 32);
        for (int kt = 0; kt < 64; ++kt) {
            const short* crow = cbh + ((size_t)q * NK + kt * 16 + row16) * ND + grp * 8;
            short8 b0 = *(const short8*)(crow);
            short8 b1 = *(const short8*)(crow + 32);
            f32x4 acc = {0.f, 0.f, 0.f, 0.f};
            acc = __builtin_amdgcn_mfma_f32_16x16x32_bf16(a0, b0, acc, 0, 0, 0);
            acc = __builtin_amdgcn_mfma_f32_16x16x32_bf16(a1, b1, acc, 0, 0, 0);
            // pack non-divergently; C row r (grp0 lanes) = h0+r, col = k
            unsigned px = bf16_rne(acc[0]) | (bf16_rne(acc[1]) << 16);
            unsigned py = bf16_rne(acc[2]) | (bf16_rne(acc[3]) << 16);
            if (grp == 0) {
                uint2 pk; pk.x = px; pk.y = py;
                Pl[q * NK + kt * 16 + row16] = pk;
            }
        }
    }

    // bias epilogue: bsum[hh] = sum_q bias[q][h0+hh]  (f32, exact)
    float bsum[4];
#pragma unroll
    for (int hh = 0; hh < 4; ++hh) {
        float s = 0.f;
#pragma unroll
        for (int q = 0; q < NQ; ++q) s += bias[q * NH + h0 + hh];
        bsum[hh] = s;
    }
    __syncthreads();

    // ---- Phase 2: gather (verbatim R12 body + bsum) ----
#pragma unroll 1
    for (int jj = 0; jj < 16; ++jj) {
        int b  = jj >> 1;
        int t0 = th * (NT / 2) + (jj & 1) * 2048 + tid * 4;
        vfloat2 acc[4][2];
#pragma unroll
        for (int tt = 0; tt < 4; ++tt) {
            acc[tt][0] = (vfloat2){0.f, 0.f};
            acc[tt][1] = (vfloat2){0.f, 0.f};
        }
#pragma unroll
        for (int q = 0; q < NQ; ++q) {
            int4 cc = *(const int4*)(codes + ((size_t)q * NB + b) * NT + t0);
#pragma unroll
            for (int tt = 0; tt < 4; ++tt) {
                int c = (tt == 0) ? cc.x : (tt == 1) ? cc.y : (tt == 2) ? cc.z : cc.w;
                uint2 v = Pl[q * NK + c];  // ds_read_b64: 4 bf16 h-values
                acc[tt][0] += (vfloat2){__uint_as_float(v.x << 16), __uint_as_float(v.x)};
                acc[tt][1] += (vfloat2){__uint_as_float(v.y << 16), __uint_as_float(v.y)};
            }
        }
#pragma unroll
        for (int hh = 0; hh < 4; ++hh) {
            vfloat4 o;
            o[0] = acc[0][hh >> 1][hh & 1] + bsum[hh];
            o[1] = acc[1][hh >> 1][hh & 1] + bsum[hh];
            o[2] = acc[2][hh >> 1][hh & 1] + bsum[hh];
            o[3] = acc[3][hh >> 1][hh & 1] + bsum[hh];
            vfloat4* dstp = (vfloat4*)(out + ((size_t)b * NH + (h0 + hh)) * NT + t0);
            __builtin_nontemporal_store(o, dstp);
        }
    }
}

extern "C" void kernel_launch(void* const* d_in, const int* in_sizes, int n_in,
                              void* d_out, int out_size, void* d_ws, size_t ws_size,
                              hipStream_t stream) {
    const int*   codes = (const int*)d_in[0];    // [Q,B,T] int32
    const float* cb    = (const float*)d_in[1];  // [Q,K,D] f32
    const float* W     = (const float*)d_in[2];  // [Q,H,D] f32
    const float* bias  = (const float*)d_in[3];  // [Q,H] f32
    float*       out   = (float*)d_out;          // [B,H,T] f32

    // ws offsets exactly as the last passing rounds (R11/R12)
    uint4* cbh = (uint4*)((char*)d_ws + (16u << 20));   // 1 MB bf16
    uint4* Wh  = (uint4*)((char*)d_ws + (17u << 20));   // 1 MB bf16

    to_bf16<<<512, 256, 0, stream>>>(cb, W, cbh, Wh);
    fused_rvq<<<512, 512, 0, stream>>>(codes, (const short*)cbh, (const short*)Wh,
                                       bias, out);
}

// Round 16
// 74.099 us; speedup vs baseline: 1.4744x; 1.4744x over previous
//
#include <hip/hip_runtime.h>
#include <hip/hip_bf16.h>

// Problem dims (fixed by reference setup_inputs)
#define NQ 8
#define NK 1024
#define ND 64
#define NH 1024
#define NB 8
#define NT 8192

typedef float  vfloat4 __attribute__((ext_vector_type(4)));
typedef float  vfloat2 __attribute__((ext_vector_type(2)));
typedef float  f32x4   __attribute__((ext_vector_type(4)));
typedef short  short8  __attribute__((ext_vector_type(8)));

// HW packed f32->bf16 (RNE). Plain VALU asm (R9-R12 verified).
__device__ __forceinline__ unsigned cvt_pk_bf16(float lo, float hi) {
    unsigned r;
    asm("v_cvt_pk_bf16_f32 %0, %1, %2" : "=v"(r) : "v"(lo), "v"(hi));
    return r;
}

// ------------- Kernel 0: convert cb and W to bf16 (exact R11) --------------
__global__ __launch_bounds__(256) void to_bf16(const float* __restrict__ cb,
                                               const float* __restrict__ W,
                                               uint4* __restrict__ cbh,
                                               uint4* __restrict__ Wh) {
    int half = blockIdx.x >> 8;
    int i    = ((blockIdx.x & 255) << 8) + threadIdx.x;  // 0..65535
    const float4* src = (const float4*)(half ? W : cb);
    float4 a = src[i * 2], b = src[i * 2 + 1];
    uint4 o;
    o.x = cvt_pk_bf16(a.x, a.y);
    o.y = cvt_pk_bf16(a.z, a.w);
    o.z = cvt_pk_bf16(b.x, b.y);
    o.w = cvt_pk_bf16(b.z, b.w);
    (half ? Wh : cbh)[i] = o;
}

// ------------- Kernel 1: build projected codebook via MFMA (R11 body) ------
// Same verified kernel as R11; ONLY the store index changed: Pt is now laid
// out 8h-per-row: uint4 row = (hg8, q, k) holding h = hg8*8 + 0..7; lane grp
// writes its uint2 (4h) into word (hg&1) of that row.
__global__ __launch_bounds__(256) void build_Pt(const short* __restrict__ cbh,
                                                const short* __restrict__ Wh,
                                                const float* __restrict__ bias,
                                                uint2* __restrict__ Pt2) {
    int q    = blockIdx.x >> 8;        // 8
    int rest = blockIdx.x & 255;
    int hb   = rest >> 4;              // 16 h-blocks of 64
    int kb   = rest & 15;              // 16 k-blocks of 64
    int wave = threadIdx.x >> 6, lane = threadIdx.x & 63;
    int h_tile = hb * 64 + wave * 16;
    int row16 = lane & 15, grp = lane >> 4;  // grp 0..3

    short8 afrag[2];
    const short* wrow = Wh + ((size_t)q * NH + h_tile + row16) * ND + grp * 8;
    afrag[0] = *(const short8*)(wrow);
    afrag[1] = *(const short8*)(wrow + 32);

    float bvals[4];
#pragma unroll
    for (int r = 0; r < 4; ++r) bvals[r] = bias[q * NH + h_tile + grp * 4 + r];

    int k0 = kb * 64;
    const short* cbase = cbh + ((size_t)q * NK + k0 + row16) * ND + grp * 8;
    int hg = (h_tile >> 2) + grp;      // 4h-group index 0..255

#pragma unroll
    for (int t = 0; t < 4; ++t) {
        const short* crow = cbase + (size_t)t * 16 * ND;
        short8 b0 = *(const short8*)(crow);
        short8 b1 = *(const short8*)(crow + 32);
        f32x4 acc = {0.f, 0.f, 0.f, 0.f};
        acc = __builtin_amdgcn_mfma_f32_16x16x32_bf16(afrag[0], b0, acc, 0, 0, 0);
        acc = __builtin_amdgcn_mfma_f32_16x16x32_bf16(afrag[1], b1, acc, 0, 0, 0);
        int k = k0 + t * 16 + row16;
        uint2 pk;
        pk.x = cvt_pk_bf16(acc[0] + bvals[0], acc[1] + bvals[1]);
        pk.y = cvt_pk_bf16(acc[2] + bvals[2], acc[3] + bvals[3]);
        // 8h-interleaved: uint4 row (hg>>1, q, k), word hg&1
        Pt2[((((size_t)(hg >> 1) * NQ) + q) * NK + k) * 2 + (hg & 1)] = pk;
    }
}

// ------------- Kernel 2: gather-sum, 8h per ds_read_b128 -------------------
// out[b,h,t] = sum_q P[q, codes[q,b,t], h]   (bias folded into P)
// R15 decomposition: gather is LDS-instruction/conflict-bound (R11: 134M
// random ds_read_b64 ~= 8192 wave-instrs/CU at ~20cyc ~= 70us). This kernel
// halves the instruction count: 128KB LDS slice [q][k] -> uint4 of 8 bf16 h;
// one b128 read serves 8 h. Grid 256 = 128 hg8 x 2 t-halves, 1024 thr,
// 1 block/CU (16 waves). Odd-h lanes carry <2^-8 relative low-bit noise
// (accepted since R12). Coalesced nt float4 stores.
__global__ __launch_bounds__(1024) void gather_sum8(const int* __restrict__ codes,
                                                    const uint4* __restrict__ Pt4,
                                                    float* __restrict__ out) {
    int th  = blockIdx.x & 1;
    int hg8 = blockIdx.x >> 1;     // 0..127
    int tid = threadIdx.x;

    __shared__ uint4 Pl[NQ * NK];  // 128 KB
    const uint4* src = Pt4 + (size_t)hg8 * NQ * NK;
#pragma unroll
    for (int i = 0; i < 8; ++i) Pl[tid + i * 1024] = src[tid + i * 1024];
    __syncthreads();

    int h0 = hg8 * 8;
    int t0 = th * (NT / 2) + tid * 4;

#pragma unroll 1
    for (int b = 0; b < NB; ++b) {
        // acc[tt][p]: vfloat2 = (h 2p exact, h 2p+1 + low-bit noise)
        vfloat2 acc[4][4];
#pragma unroll
        for (int tt = 0; tt < 4; ++tt)
#pragma unroll
            for (int p = 0; p < 4; ++p) acc[tt][p] = (vfloat2){0.f, 0.f};

#pragma unroll
        for (int q = 0; q < NQ; ++q) {
            int4 cc = *(const int4*)(codes + ((size_t)q * NB + b) * NT + t0);
#pragma unroll
            for (int tt = 0; tt < 4; ++tt) {
                int c = (tt == 0) ? cc.x : (tt == 1) ? cc.y : (tt == 2) ? cc.z : cc.w;
                uint4 v = Pl[q * NK + c];   // ds_read_b128: 8 bf16 h-values
                acc[tt][0] += (vfloat2){__uint_as_float(v.x << 16), __uint_as_float(v.x)};
                acc[tt][1] += (vfloat2){__uint_as_float(v.y << 16), __uint_as_float(v.y)};
                acc[tt][2] += (vfloat2){__uint_as_float(v.z << 16), __uint_as_float(v.z)};
                acc[tt][3] += (vfloat2){__uint_as_float(v.w << 16), __uint_as_float(v.w)};
            }
        }
#pragma unroll
        for (int hh = 0; hh < 8; ++hh) {
            vfloat4 o;
            o[0] = acc[0][hh >> 1][hh & 1];
            o[1] = acc[1][hh >> 1][hh & 1];
            o[2] = acc[2][hh >> 1][hh & 1];
            o[3] = acc[3][hh >> 1][hh & 1];
            vfloat4* dstp = (vfloat4*)(out + ((size_t)b * NH + (h0 + hh)) * NT + t0);
            __builtin_nontemporal_store(o, dstp);
        }
    }
}

extern "C" void kernel_launch(void* const* d_in, const int* in_sizes, int n_in,
                              void* d_out, int out_size, void* d_ws, size_t ws_size,
                              hipStream_t stream) {
    const int*   codes = (const int*)d_in[0];    // [Q,B,T] int32
    const float* cb    = (const float*)d_in[1];  // [Q,K,D] f32
    const float* W     = (const float*)d_in[2];  // [Q,H,D] f32
    const float* bias  = (const float*)d_in[3];  // [Q,H] f32
    float*       out   = (float*)d_out;          // [B,H,T] f32

    uint2* Pt2 = (uint2*)d_ws;                          // 16 MB (8h rows)
    uint4* cbh = (uint4*)((char*)d_ws + (16u << 20));   // 1 MB bf16
    uint4* Wh  = (uint4*)((char*)d_ws + (17u << 20));   // 1 MB bf16

    to_bf16<<<512, 256, 0, stream>>>(cb, W, cbh, Wh);
    build_Pt<<<2048, 256, 0, stream>>>((const short*)cbh, (const short*)Wh, bias, Pt2);
    gather_sum8<<<256, 1024, 0, stream>>>(codes, (const uint4*)Pt2, out);
}